// Round 8
// baseline (39.016 us; speedup 1.0000x reference)
//
#include <hip/hip_runtime.h>
#include <math.h>

typedef float v2f __attribute__((ext_vector_type(2)));

constexpr int NW = 14;
constexpr int DIM = 1 << NW;      // 16384
constexpr int BATCH = 256;
constexpr int NT = 1024;          // 16 waves; 16 amps/thread as 8 v2f pairs

// XOR bank swizzle on float index; folds bits 5..8, 9..12, 13 into bits 1..4
// ONLY (bit 0 preserved -> P=0 pairs stay LDS-adjacent and 8B-aligned).
__device__ __host__ constexpr int swz(int i) {
    return i ^ (((i >> 5) & 15) << 1) ^ (((i >> 9) & 15) << 1) ^ (((i >> 13) & 1) << 1);
}

// Scatter thread id t (10 bits) to global bit positions (Q0..Q5 lane, Q6..Q9 wave).
template<int Q0,int Q1,int Q2,int Q3,int Q4,int Q5,int Q6,int Q7,int Q8,int Q9>
__device__ __forceinline__ int scat10(int t) {
    return ((t & 1) << Q0) | (((t >> 1) & 1) << Q1) | (((t >> 2) & 1) << Q2) |
           (((t >> 3) & 1) << Q3) | (((t >> 4) & 1) << Q4) | (((t >> 5) & 1) << Q5) |
           (((t >> 6) & 1) << Q6) | (((t >> 7) & 1) << Q7) | (((t >> 8) & 1) << Q8) |
           (((t >> 9) & 1) << Q9);
}

// ---------------------------------------------------------------------------
// Packed fp32 primitives (VOP3P), proven in R7.
__device__ __forceinline__ v2f pkmul_lo(v2f P, v2f B) {
    v2f d; asm("v_pk_mul_f32 %0, %1, %2 op_sel:[0,0] op_sel_hi:[0,1]"
               : "=v"(d) : "v"(P), "v"(B)); return d;
}
__device__ __forceinline__ v2f pkmul_hi(v2f P, v2f B) {
    v2f d; asm("v_pk_mul_f32 %0, %1, %2 op_sel:[1,0] op_sel_hi:[1,1]"
               : "=v"(d) : "v"(P), "v"(B)); return d;
}
__device__ __forceinline__ v2f pkfma_lo(v2f P, v2f B, v2f C) {
    v2f d; asm("v_pk_fma_f32 %0, %1, %2, %3 op_sel:[0,0,0] op_sel_hi:[0,1,1]"
               : "=v"(d) : "v"(P), "v"(B), "v"(C)); return d;
}
__device__ __forceinline__ v2f pkfma_hi(v2f P, v2f B, v2f C) {
    v2f d; asm("v_pk_fma_f32 %0, %1, %2, %3 op_sel:[1,0,0] op_sel_hi:[1,1,1]"
               : "=v"(d) : "v"(P), "v"(B), "v"(C)); return d;
}
__device__ __forceinline__ v2f pkfmn_hi(v2f P, v2f B, v2f C) {
    v2f d; asm("v_pk_fma_f32 %0, %1, %2, %3 op_sel:[1,0,0] op_sel_hi:[1,1,1] neg_lo:[1,0,0] neg_hi:[1,0,0]"
               : "=v"(d) : "v"(P), "v"(B), "v"(C)); return d;
}

// ---------------------------------------------------------------------------
// Uniform packed gate on slot bits (JW wire, JT target); pk dim spectator.
template<int JW, int JT>
__device__ __forceinline__ void gate_u(v2f (&pr)[8], v2f (&pi)[8],
                                       v2f Y, v2f Z, v2f X)
{
    constexpr int BW = 1 << JW, BT = 1 << JT, JF = 3 - JW - JT;
    #pragma unroll
    for (int m = 0; m < 2; ++m) {
        const int l00 = m << JF;
        const int iA = l00, iB = l00 | BW, iC = l00 | BT, iD = l00 | BW | BT;

        v2f a00r = pr[iA], a00i = pi[iA];
        v2f a10r = pr[iB], a10i = pi[iB];
        v2f a01r = pr[iC], a01i = pi[iC];
        v2f a11r = pr[iD], a11i = pi[iD];

        v2f v0r = pkfmn_hi(Y, a10r, pkmul_lo(Y, a00r));
        v2f v0i = pkfmn_hi(Y, a10i, pkmul_lo(Y, a00i));
        v2f v1r = pkfma_lo(Y, a10r, pkmul_hi(Y, a00r));
        v2f v1i = pkfma_lo(Y, a10i, pkmul_hi(Y, a00i));
        v2f u0r = pkfmn_hi(Y, a11r, pkmul_lo(Y, a01r));
        v2f u0i = pkfmn_hi(Y, a11i, pkmul_lo(Y, a01i));
        v2f u1r = pkfma_lo(Y, a11r, pkmul_hi(Y, a01r));
        v2f u1i = pkfma_lo(Y, a11i, pkmul_hi(Y, a01i));

        v2f b00r = pkfma_hi(Z, v0i, pkmul_lo(Z, v0r));
        v2f b00i = pkfmn_hi(Z, v0r, pkmul_lo(Z, v0i));
        v2f b10r = pkfmn_hi(Z, v1i, pkmul_lo(Z, v1r));
        v2f b10i = pkfma_hi(Z, v1r, pkmul_lo(Z, v1i));
        v2f b01r = pkfma_hi(Z, u0i, pkmul_lo(Z, u0r));
        v2f b01i = pkfmn_hi(Z, u0r, pkmul_lo(Z, u0i));
        v2f b11r = pkfmn_hi(Z, u1i, pkmul_lo(Z, u1r));
        v2f b11i = pkfma_hi(Z, u1r, pkmul_lo(Z, u1i));

        pr[iA] = pkfma_hi(X, b11i, pkmul_lo(X, b00r));
        pi[iA] = pkfmn_hi(X, b11r, pkmul_lo(X, b00i));
        pr[iB] = pkfma_lo(X, b11r, pkmul_hi(X, b00i));
        pi[iB] = pkfmn_hi(X, b00r, pkmul_lo(X, b11i));
        pr[iC] = pkfma_hi(X, b10i, pkmul_lo(X, b01r));
        pi[iC] = pkfmn_hi(X, b10r, pkmul_lo(X, b01i));
        pr[iD] = pkfma_lo(X, b10r, pkmul_hi(X, b01i));
        pi[iD] = pkfmn_hi(X, b01r, pkmul_lo(X, b10i));
    }
}

// ---------------------------------------------------------------------------
// Exchange slot bit J with lane bit 5 / lane bit 4 (proven R4-R7).
template<int J>
__device__ __forceinline__ void swap_l5(v2f (&pr)[8], v2f (&pi)[8]) {
    constexpr int jA = (J == 0) ? 1 : 0, jB = (J == 2) ? 1 : 2;
    #pragma unroll
    for (int m = 0; m < 4; ++m) {
        const int l0 = ((m & 1) << jA) | (((m >> 1) & 1) << jB);
        const int l1 = l0 | (1 << J);
        { float a=pr[l0].x, c=pr[l1].x; asm("s_nop 1\n\tv_permlane32_swap_b32 %0, %1":"+v"(a),"+v"(c)); pr[l0].x=a; pr[l1].x=c; }
        { float a=pr[l0].y, c=pr[l1].y; asm("s_nop 1\n\tv_permlane32_swap_b32 %0, %1":"+v"(a),"+v"(c)); pr[l0].y=a; pr[l1].y=c; }
        { float a=pi[l0].x, c=pi[l1].x; asm("s_nop 1\n\tv_permlane32_swap_b32 %0, %1":"+v"(a),"+v"(c)); pi[l0].x=a; pi[l1].x=c; }
        { float a=pi[l0].y, c=pi[l1].y; asm("s_nop 1\n\tv_permlane32_swap_b32 %0, %1":"+v"(a),"+v"(c)); pi[l0].y=a; pi[l1].y=c; }
    }
}

template<int J>
__device__ __forceinline__ void swap_l4(v2f (&pr)[8], v2f (&pi)[8]) {
    constexpr int jA = (J == 0) ? 1 : 0, jB = (J == 2) ? 1 : 2;
    #pragma unroll
    for (int m = 0; m < 4; ++m) {
        const int l0 = ((m & 1) << jA) | (((m >> 1) & 1) << jB);
        const int l1 = l0 | (1 << J);
        { float a=pr[l0].x, c=pr[l1].x; asm("s_nop 1\n\tv_permlane16_swap_b32 %0, %1":"+v"(a),"+v"(c)); pr[l0].x=a; pr[l1].x=c; }
        { float a=pr[l0].y, c=pr[l1].y; asm("s_nop 1\n\tv_permlane16_swap_b32 %0, %1":"+v"(a),"+v"(c)); pr[l0].y=a; pr[l1].y=c; }
        { float a=pi[l0].x, c=pi[l1].x; asm("s_nop 1\n\tv_permlane16_swap_b32 %0, %1":"+v"(a),"+v"(c)); pi[l0].x=a; pi[l1].x=c; }
        { float a=pi[l0].y, c=pi[l1].y; asm("s_nop 1\n\tv_permlane16_swap_b32 %0, %1":"+v"(a),"+v"(c)); pi[l0].y=a; pi[l1].y=c; }
    }
}

// ---------------------------------------------------------------------------
// LDS round trips. S0,S1,S2 = global positions of slot bits.
template<int S0,int S1,int S2>
__device__ __forceinline__ void store64(float* re, float* im,
                                        const v2f (&pr)[8], const v2f (&pi)[8], int sb) {
    #pragma unroll
    for (int k = 0; k < 8; ++k) {
        const int c = swz(((k & 1) << S0) | (((k >> 1) & 1) << S1) | (((k >> 2) & 1) << S2));
        const int a = sb ^ c;
        *(v2f*)(re + a) = pr[k];
        *(v2f*)(im + a) = pi[k];
    }
}

template<int S0,int S1,int S2>
__device__ __forceinline__ void load64(const float* re, const float* im,
                                       v2f (&pr)[8], v2f (&pi)[8], int sb) {
    #pragma unroll
    for (int k = 0; k < 8; ++k) {
        const int c = swz(((k & 1) << S0) | (((k >> 1) & 1) << S1) | (((k >> 2) & 1) << S2));
        const int a = sb ^ c;
        pr[k] = *(const v2f*)(re + a);
        pi[k] = *(const v2f*)(im + a);
    }
}

// PB = packed-bit position (b32 path).
template<int S0,int S1,int S2,int PB>
__device__ __forceinline__ void store32(float* re, float* im,
                                        const v2f (&pr)[8], const v2f (&pi)[8], int sb) {
    #pragma unroll
    for (int k = 0; k < 8; ++k) {
        const int cc = ((k & 1) << S0) | (((k >> 1) & 1) << S1) | (((k >> 2) & 1) << S2);
        const int a0 = sb ^ swz(cc);
        const int a1 = sb ^ swz(cc | (1 << PB));
        re[a0] = pr[k].x; re[a1] = pr[k].y;
        im[a0] = pi[k].x; im[a1] = pi[k].y;
    }
}

template<int S0,int S1,int S2,int PB>
__device__ __forceinline__ void load32(const float* re, const float* im,
                                       v2f (&pr)[8], v2f (&pi)[8], int sb) {
    #pragma unroll
    for (int k = 0; k < 8; ++k) {
        const int cc = ((k & 1) << S0) | (((k >> 1) & 1) << S1) | (((k >> 2) & 1) << S2);
        const int a0 = sb ^ swz(cc);
        const int a1 = sb ^ swz(cc | (1 << PB));
        pr[k].x = re[a0]; pr[k].y = re[a1];
        pi[k].x = im[a0]; pi[k].y = im[a1];
    }
}

__global__ __launch_bounds__(NT, 1) void qsim(const float* __restrict__ state,
                                              const float* __restrict__ params,
                                              const float* __restrict__ head_w,
                                              const float* __restrict__ head_b,
                                              float* __restrict__ out)
{
    __shared__ float re[DIM];           // 64 KiB
    __shared__ float im[DIM];           // 64 KiB
    __shared__ float2 csv[NW * 3 * 2];  // (cos,sin) of half-angles, 84 gates
    __shared__ float partial[NT / 64];

    const int t = threadIdx.x;
    const int b = blockIdx.x;

    v2f pr[8], pi[8];

    // ---- Segment A layout A1: P=0, S=[13,12,11],
    //      L: t0->1,t1->2,t2->3,t3->4, l4->9, l5->10; W: t6->5,t7->6,t8->7,t9->8.
    const float2* __restrict__ sp2 = (const float2*)(state + (size_t)b * DIM);
    const int tbA = scat10<1,2,3,4,9,10,5,6,7,8>(t);
    #pragma unroll
    for (int k = 0; k < 8; ++k) {
        const int idx = tbA | ((k & 1) << 13) | (((k >> 1) & 1) << 12) | (((k >> 2) & 1) << 11);
        const float2 v = sp2[idx >> 1];
        pr[k] = v2f{v.x, v.y};
        pi[k] = v2f{0.0f, 0.0f};
    }

    if (t < NW * 3 * 2) {
        float sv, cv;
        sincosf(params[t] * 0.5f, &sv, &cv);
        csv[t] = make_float2(cv, sv);
    }
    __syncthreads();

#define GU(JW, JT, G) do {                                              \
        v2f Y = *(const v2f*)&csv[(G)*3+0];                             \
        v2f Z = *(const v2f*)&csv[(G)*3+1];                             \
        v2f X = *(const v2f*)&csv[(G)*3+2];                             \
        gate_u<JW, JT>(pr, pi, Y, Z, X);                                \
    } while (0)

    // ---- Segment A: L1 gates (13,12),(12,11),(11,10),(10,9) ----
    GU(0, 1, 0);          // (13,12)
    GU(1, 2, 1);          // (12,11)
    swap_l5<0>(pr, pi);   // k0:13(done) <-> l5:10  => S=[10,12,11], l5->13
    GU(2, 0, 2);          // (11,10)
    swap_l4<1>(pr, pi);   // k1:12(done) <-> l4:9   => S=[10,9,11], l4->12
    GU(0, 1, 3);          // (10,9)
    // End-A: S=[10,9,11]; L: 1,2,3,4, l4->12, l5->13; W: 5,6,7,8.
    store64<10,9,11>(re, im, pr, pi, swz(scat10<1,2,3,4,12,13,5,6,7,8>(t)));
    __syncthreads();      // GLOBAL 1

    // ---- Segment B: L1 gates (9,8)..(2,1) ----
    // B1: P=0, S=[9,8,7]; L: t0->4,t1->3,t2->2,t3->1, l4->6, l5->5; W: 13,12,11,10.
    load64<9,8,7>(re, im, pr, pi, swz(scat10<4,3,2,1,6,5,13,12,11,10>(t)));
    GU(0, 1, 4);          // (9,8)
    GU(1, 2, 5);          // (8,7)
    swap_l4<0>(pr, pi);   // k0:9 <-> l4:6  => S=[6,8,7], l4->9
    GU(2, 0, 6);          // (7,6)
    swap_l5<1>(pr, pi);   // k1:8 <-> l5:5  => S=[6,5,7], l5->8
    GU(0, 1, 7);          // (6,5)
    // Local reshuffle R1 (wave bits 13,12,11,10 unchanged -> no barrier).
    store64<6,5,7>(re, im, pr, pi, swz(scat10<4,3,2,1,9,8,13,12,11,10>(t)));
    asm volatile("" ::: "memory");
    // B2: S=[5,4,3]; L: t0->7,t1->6,t2->9,t3->8, l4->2, l5->1.
    load64<5,4,3>(re, im, pr, pi, swz(scat10<7,6,9,8,2,1,13,12,11,10>(t)));
    GU(0, 1, 8);          // (5,4)
    GU(1, 2, 9);          // (4,3)
    swap_l4<0>(pr, pi);   // k0:5 <-> l4:2  => S=[2,4,3], l4->5
    GU(2, 0, 10);         // (3,2)
    swap_l5<1>(pr, pi);   // k1:4 <-> l5:1  => S=[2,1,3], l5->4
    GU(0, 1, 11);         // (2,1)
    // End-B: S=[2,1,3]; L: t0->7,t1->6,t2->9,t3->8, l4->5, l5->4; W: 13,12,11,10.
    store64<2,1,3>(re, im, pr, pi, swz(scat10<7,6,9,8,5,4,13,12,11,10>(t)));
    __syncthreads();      // GLOBAL 2

    // ---- Segment C: L1 (1,0),(0,13); L2 (13,12),(12,11),(11,10),(10,9) ----
    // C1: P=4, S=[1,0,13]; L: t0->3,t1->2,t2->10,t3->9, l4->12, l5->11; W: 8,7,6,5.
    load32<1,0,13,4>(re, im, pr, pi, swz(scat10<3,2,10,9,12,11,8,7,6,5>(t)));
    GU(0, 1, 12);         // (1,0)
    GU(1, 2, 13);         // (0,13)
    swap_l4<0>(pr, pi);   // k0:1 <-> l4:12 => S=[12,0,13], l4->1
    GU(2, 0, 14);         // (13,12)
    swap_l5<1>(pr, pi);   // k1:0 <-> l5:11 => S=[12,11,13], l5->0
    GU(0, 1, 15);         // (12,11)
    // Local reshuffle R2 (wave bits 8,7,6,5 unchanged).
    store32<12,11,13,4>(re, im, pr, pi, swz(scat10<3,2,10,9,1,0,8,7,6,5>(t)));
    asm volatile("" ::: "memory");
    // C2: S=[11,10,9]; L: t0->3,t1->2,t2->13,t3->12, l4->1, l5->0.
    {
        const int sbC2 = swz(scat10<3,2,13,12,1,0,8,7,6,5>(t));
        load32<11,10,9,4>(re, im, pr, pi, sbC2);
        GU(0, 1, 16);     // (11,10)
        GU(1, 2, 17);     // (10,9)
        store32<11,10,9,4>(re, im, pr, pi, sbC2);
    }
    __syncthreads();      // GLOBAL 3

    // ---- Segment D: L2 gates (9,8)..(2,1) — same layouts as B, gates 18..25 ----
    load64<9,8,7>(re, im, pr, pi, swz(scat10<4,3,2,1,6,5,13,12,11,10>(t)));
    GU(0, 1, 18);         // (9,8)
    GU(1, 2, 19);         // (8,7)
    swap_l4<0>(pr, pi);
    GU(2, 0, 20);         // (7,6)
    swap_l5<1>(pr, pi);
    GU(0, 1, 21);         // (6,5)
    store64<6,5,7>(re, im, pr, pi, swz(scat10<4,3,2,1,9,8,13,12,11,10>(t)));
    asm volatile("" ::: "memory");
    load64<5,4,3>(re, im, pr, pi, swz(scat10<7,6,9,8,2,1,13,12,11,10>(t)));
    GU(0, 1, 22);         // (5,4)
    GU(1, 2, 23);         // (4,3)
    swap_l4<0>(pr, pi);
    GU(2, 0, 24);         // (3,2)
    swap_l5<1>(pr, pi);
    GU(0, 1, 25);         // (2,1)
    store64<2,1,3>(re, im, pr, pi, swz(scat10<7,6,9,8,5,4,13,12,11,10>(t)));
    __syncthreads();      // GLOBAL 4

    // ---- Segment E: L2 (1,0),(0,13); epilogue from registers ----
    // E1: P=2, S=[1,0,13]; L: t0->8,t1->7,t2->6,t3->5, l4->4, l5->3; W: 12,11,10,9.
    load32<1,0,13,2>(re, im, pr, pi, swz(scat10<8,7,6,5,4,3,12,11,10,9>(t)));
    GU(0, 1, 26);         // (1,0)
    GU(1, 2, 27);         // (0,13)

    // ---- Epilogue: out[b] = sum_i |amp_i|^2 * g(i) + head_b ----
    // Positions: k0->1, k1->0, k2->13; P->2;
    // t0->8,t1->7,t2->6,t3->5,t4->4,t5->3,t6->12,t7->11,t8->10,t9->9.
    float hw[NW];
    #pragma unroll
    for (int w = 0; w < NW; ++w) hw[w] = head_w[w];

    float gbase = 0.0f;
    gbase += (t & 1)   ? -hw[5]  : hw[5];    // t0 -> bit 8
    gbase += (t & 2)   ? -hw[6]  : hw[6];    // t1 -> bit 7
    gbase += (t & 4)   ? -hw[7]  : hw[7];    // t2 -> bit 6
    gbase += (t & 8)   ? -hw[8]  : hw[8];    // t3 -> bit 5
    gbase += (t & 16)  ? -hw[9]  : hw[9];    // t4 -> bit 4
    gbase += (t & 32)  ? -hw[10] : hw[10];   // t5 -> bit 3
    gbase += (t & 64)  ? -hw[1]  : hw[1];    // t6 -> bit 12
    gbase += (t & 128) ? -hw[2]  : hw[2];    // t7 -> bit 11
    gbase += (t & 256) ? -hw[3]  : hw[3];    // t8 -> bit 10
    gbase += (t & 512) ? -hw[4]  : hw[4];    // t9 -> bit 9

    v2f acc2 = {0.0f, 0.0f};
    #pragma unroll
    for (int k = 0; k < 8; ++k) {
        float g = gbase;
        g += (k & 1) ? -hw[12] : hw[12];     // k0 -> bit 1
        g += (k & 2) ? -hw[13] : hw[13];     // k1 -> bit 0
        g += (k & 4) ? -hw[0]  : hw[0];      // k2 -> bit 13
        v2f gv = {g + hw[11], g - hw[11]};   // P -> bit 2
        acc2 += (pr[k]*pr[k] + pi[k]*pi[k]) * gv;
    }
    float acc = acc2.x + acc2.y;

    #pragma unroll
    for (int off = 32; off > 0; off >>= 1) acc += __shfl_down(acc, off);
    if ((t & 63) == 0) partial[t >> 6] = acc;
    __syncthreads();
    if (t == 0) {
        float tot = 0.0f;
        #pragma unroll
        for (int k = 0; k < NT / 64; ++k) tot += partial[k];
        out[b] = tot + head_b[0];
    }
#undef GU
}

extern "C" void kernel_launch(void* const* d_in, const int* in_sizes, int n_in,
                              void* d_out, int out_size, void* d_ws, size_t ws_size,
                              hipStream_t stream) {
    const float* state  = (const float*)d_in[0];
    const float* params = (const float*)d_in[1];
    const float* head_w = (const float*)d_in[2];
    const float* head_b = (const float*)d_in[3];
    float* outp = (float*)d_out;
    qsim<<<BATCH, NT, 0, stream>>>(state, params, head_w, head_b, outp);
}

// Round 9
// 36.472 us; speedup vs baseline: 1.0698x; 1.0698x over previous
//
#include <hip/hip_runtime.h>
#include <math.h>

typedef float v2f __attribute__((ext_vector_type(2)));

constexpr int NW = 14;
constexpr int DIM = 1 << NW;      // 16384
constexpr int BATCH = 256;
constexpr int NT = 512;           // 8 waves; each thread owns 32 amplitudes (16 v2f pairs)

// LDS bank swizzle: XOR bits 9..5 into 4..0 (bijective; measured 0 conflicts in R2).
__device__ __forceinline__ int swz(int i) { return i ^ ((i >> 5) & 31); }

// ---------------------------------------------------------------------------
// Uniform packed gate: JW, JT in {0..3}; packed dim (local bit 4) is a
// spectator, so each scalar line becomes one v_pk op on both halves.
template<int JW, int JT>
__device__ __forceinline__ void gate_u(v2f (&pr)[16], v2f (&pi)[16],
                                       float cy, float sy, float c1, float s1,
                                       float cx, float sx)
{
    constexpr int BW = 1 << JW, BT = 1 << JT;
    #pragma unroll
    for (int m = 0; m < 4; ++m) {
        int l00 = 0, mm = m;
        #pragma unroll
        for (int j = 0; j < 4; ++j)
            if (j != JW && j != JT) { l00 |= (mm & 1) << j; mm >>= 1; }
        const int iA = l00, iB = l00 | BW, iC = l00 | BT, iD = l00 | BW | BT;

        v2f a00r = pr[iA], a00i = pi[iA];
        v2f a10r = pr[iB], a10i = pi[iB];
        v2f a01r = pr[iC], a01i = pi[iC];
        v2f a11r = pr[iD], a11i = pi[iD];

        // RY (real) on wire bit
        v2f v0r = cy*a00r - sy*a10r, v0i = cy*a00i - sy*a10i;
        v2f v1r = sy*a00r + cy*a10r, v1i = sy*a00i + cy*a10i;
        v2f u0r = cy*a01r - sy*a11r, u0i = cy*a01i - sy*a11i;
        v2f u1r = sy*a01r + cy*a11r, u1i = sy*a01i + cy*a11i;

        // RZ phase on wire bit
        v2f b00r = c1*v0r + s1*v0i, b00i = c1*v0i - s1*v0r;
        v2f b10r = c1*v1r - s1*v1i, b10i = c1*v1i + s1*v1r;
        v2f b01r = c1*u0r + s1*u0i, b01i = c1*u0i - s1*u0r;
        v2f b11r = c1*u1r - s1*u1i, b11i = c1*u1i + s1*u1r;

        // CNOT(w->t) then RX(w)
        v2f o00r = cx*b00r + sx*b11i, o00i = cx*b00i - sx*b11r;
        v2f o10r = sx*b00i + cx*b11r, o10i = cx*b11i - sx*b00r;
        v2f o01r = cx*b01r + sx*b10i, o01i = cx*b01i - sx*b10r;
        v2f o11r = sx*b01i + cx*b10r, o11i = cx*b10i - sx*b01r;

        pr[iA] = o00r; pi[iA] = o00i;
        pr[iB] = o10r; pi[iB] = o10i;
        pr[iC] = o01r; pi[iC] = o01i;
        pr[iD] = o11r; pi[iD] = o11i;
    }
}

// Clean packed gate: wire = local bit 0, target = packed dim (local bit 4).
__device__ __forceinline__ void gate_c(v2f (&pr)[16], v2f (&pi)[16],
                                       float cy, float sy, float c1, float s1,
                                       float cx, float sx)
{
    #pragma unroll
    for (int m = 0; m < 8; ++m) {
        const int iA = m << 1, iB = iA | 1;
        v2f Ar = pr[iA], Ai = pi[iA];   // (a00, a01)
        v2f Br = pr[iB], Bi = pi[iB];   // (a10, a11)

        // RY on wire bit (uniform over packed target dim)
        v2f Vr = cy*Ar - sy*Br, Vi = cy*Ai - sy*Bi;   // w=0 row
        v2f Wr = sy*Ar + cy*Br, Wi = sy*Ai + cy*Bi;   // w=1 row

        // RZ on wire bit
        v2f P0r = c1*Vr + s1*Vi, P0i = c1*Vi - s1*Vr;
        v2f P1r = c1*Wr - s1*Wi, P1i = c1*Wi + s1*Wr;

        v2f sP1r = {P1r.y, P1r.x};
        v2f sP1i = {P1i.y, P1i.x};

        pr[iA] = cx*P0r + sx*sP1i;   // (o00r, o01r)
        pi[iA] = cx*P0i - sx*sP1r;   // (o00i, o01i)
        pr[iB] = sx*P0i + cx*sP1r;   // (o10r, o11r)
        pi[iB] = cx*sP1i - sx*P0r;   // (o10i, o11i)
    }
}

// ---------------------------------------------------------------------------
// Scatter thread id t (9 bits) into the 9 bit-positions NOT in {P0..P4}.
template<int P0, int P1, int P2, int P3, int P4>
__device__ __forceinline__ int base_of(int t)
{
    int base = 0, j = 0;
    #pragma unroll
    for (int p = 0; p < NW; ++p) {
        if (p != P0 && p != P1 && p != P2 && p != P3 && p != P4) {
            base |= ((t >> j) & 1) << p;
            ++j;
        }
    }
    return base;
}

template<int P0, int P1, int P2, int P3, int P4>
__device__ __forceinline__ int off_of(int l)
{
    return ((l & 1) << P0) | (((l >> 1) & 1) << P1) | (((l >> 2) & 1) << P2) |
           (((l >> 3) & 1) << P3) | (((l >> 4) & 1) << P4);
}

template<int P0, int P1, int P2, int P3, int P4>
__device__ __forceinline__ void lds_load_pk(const float* re, const float* im,
                                            v2f (&pr)[16], v2f (&pi)[16], int base)
{
    #pragma unroll
    for (int k = 0; k < 16; ++k) {
        const int s0 = swz(base | off_of<P0, P1, P2, P3, P4>(k));
        const int s1_ = swz(base | off_of<P0, P1, P2, P3, P4>(k | 16));
        pr[k] = v2f{re[s0], re[s1_]};
        pi[k] = v2f{im[s0], im[s1_]};
    }
}

template<int P0, int P1, int P2, int P3, int P4>
__device__ __forceinline__ void lds_store_pk(float* re, float* im,
                                             const v2f (&pr)[16], const v2f (&pi)[16], int base)
{
    #pragma unroll
    for (int k = 0; k < 16; ++k) {
        const int s0 = swz(base | off_of<P0, P1, P2, P3, P4>(k));
        const int s1_ = swz(base | off_of<P0, P1, P2, P3, P4>(k | 16));
        re[s0] = pr[k].x; re[s1_] = pr[k].y;
        im[s0] = pi[k].x; im[s1_] = pi[k].y;
    }
}

__global__ __launch_bounds__(NT, 1) void qsim(const float* __restrict__ state,
                                              const float* __restrict__ params,
                                              const float* __restrict__ head_w,
                                              const float* __restrict__ head_b,
                                              float* __restrict__ out)
{
    __shared__ float re[DIM];           // 64 KiB
    __shared__ float im[DIM];           // 64 KiB
    __shared__ float2 csv[NW * 3 * 2];  // (cos, sin) of half-angles, 84 gates
    __shared__ float partial[NT / 64];

    const int t = threadIdx.x;
    const int b = blockIdx.x;

    v2f pr[16], pi[16];

    // Pass A register layout: P = <10,11,12,13,9>, base = t (bits 0..8).
    const float* __restrict__ sp = state + (size_t)b * DIM;
    #pragma unroll
    for (int k = 0; k < 16; ++k) {
        pr[k] = v2f{sp[t | (k << 10)], sp[t | (k << 10) | 512]};
        pi[k] = v2f{0.0f, 0.0f};
    }

    if (t < NW * 3 * 2) {
        float sv, cv;
        sincosf(params[t] * 0.5f, &sv, &cv);
        csv[t] = make_float2(cv, sv);
    }
    __syncthreads();

#define GATEU(JW, JT, G) do {                                           \
        float2 vy = csv[(G) * 3 + 0];                                   \
        float2 vz = csv[(G) * 3 + 1];                                   \
        float2 vx = csv[(G) * 3 + 2];                                   \
        gate_u<JW, JT>(pr, pi, vy.x, vy.y, vz.x, vz.y, vx.x, vx.y);     \
    } while (0)
#define GATEC(G) do {                                                   \
        float2 vy = csv[(G) * 3 + 0];                                   \
        float2 vz = csv[(G) * 3 + 1];                                   \
        float2 vx = csv[(G) * 3 + 2];                                   \
        gate_c(pr, pi, vy.x, vy.y, vz.x, vz.y, vx.x, vx.y);             \
    } while (0)

    // Pass A: L1 wires 0-3, P=<10,11,12,13,9>, gates 0..3
    GATEU(3, 2, 0); GATEU(2, 1, 1); GATEU(1, 0, 2); GATEC(3);
    lds_store_pk<10, 11, 12, 13, 9>(re, im, pr, pi, base_of<10, 11, 12, 13, 9>(t));
    __syncthreads();

    // Pass B: L1 wires 4-7, P=<6,7,8,9,5>, gates 4..7
    {
        const int base = base_of<6, 7, 8, 9, 5>(t);
        lds_load_pk<6, 7, 8, 9, 5>(re, im, pr, pi, base);
        GATEU(3, 2, 4); GATEU(2, 1, 5); GATEU(1, 0, 6); GATEC(7);
        lds_store_pk<6, 7, 8, 9, 5>(re, im, pr, pi, base);
    }
    __syncthreads();

    // Pass C: L1 wires 8-11, P=<2,3,4,5,1>, gates 8..11
    {
        const int base = base_of<2, 3, 4, 5, 1>(t);
        lds_load_pk<2, 3, 4, 5, 1>(re, im, pr, pi, base);
        GATEU(3, 2, 8); GATEU(2, 1, 9); GATEU(1, 0, 10); GATEC(11);
        lds_store_pk<2, 3, 4, 5, 1>(re, im, pr, pi, base);
    }
    __syncthreads();

    // Pass D: L1 wires 12,13 + L2 wires 0,1, P=<12,13,0,1,11>, gates 12..15
    {
        const int base = base_of<12, 13, 0, 1, 11>(t);
        lds_load_pk<12, 13, 0, 1, 11>(re, im, pr, pi, base);
        GATEU(3, 2, 12); GATEU(2, 1, 13); GATEU(1, 0, 14); GATEC(15);
        lds_store_pk<12, 13, 0, 1, 11>(re, im, pr, pi, base);
    }
    __syncthreads();

    // Pass E: L2 wires 2-5, P=<8,9,10,11,7>, gates 16..19
    {
        const int base = base_of<8, 9, 10, 11, 7>(t);
        lds_load_pk<8, 9, 10, 11, 7>(re, im, pr, pi, base);
        GATEU(3, 2, 16); GATEU(2, 1, 17); GATEU(1, 0, 18); GATEC(19);
        lds_store_pk<8, 9, 10, 11, 7>(re, im, pr, pi, base);
    }
    __syncthreads();

    // Pass F: L2 wires 6-9, P=<4,5,6,7,3>, gates 20..23
    {
        const int base = base_of<4, 5, 6, 7, 3>(t);
        lds_load_pk<4, 5, 6, 7, 3>(re, im, pr, pi, base);
        GATEU(3, 2, 20); GATEU(2, 1, 21); GATEU(1, 0, 22); GATEC(23);
        lds_store_pk<4, 5, 6, 7, 3>(re, im, pr, pi, base);
    }
    __syncthreads();

    // Pass G: L2 wires 10-13, P=<0,1,2,3,13>, gates 24..27; epilogue from regs.
    {
        const int base = base_of<0, 1, 2, 3, 13>(t);
        lds_load_pk<0, 1, 2, 3, 13>(re, im, pr, pi, base);
        GATEU(3, 2, 24); GATEU(2, 1, 25); GATEU(1, 0, 26); GATEC(27);
    }

    // Epilogue: out[b] = sum_i |amp_i|^2 * g(i) + head_b.
    // k bits 0..3 -> global bits 0..3 -> wires 13,12,11,10; packed half -> bit 13
    // -> wire 0; thread bits -> global 4..12 -> wires 9..1.
    float hw[NW];
    #pragma unroll
    for (int w = 0; w < NW; ++w) hw[w] = head_w[w];

    float gbase = 0.0f;
    #pragma unroll
    for (int j = 0; j < 9; ++j) {
        float h = hw[9 - j];
        gbase += ((t >> j) & 1) ? -h : h;
    }

    v2f acc2 = {0.0f, 0.0f};
    #pragma unroll
    for (int k = 0; k < 16; ++k) {
        float gk = gbase;
        gk += (k & 1) ? -hw[13] : hw[13];
        gk += (k & 2) ? -hw[12] : hw[12];
        gk += (k & 4) ? -hw[11] : hw[11];
        gk += (k & 8) ? -hw[10] : hw[10];
        v2f g = {gk + hw[0], gk - hw[0]};
        acc2 += (pr[k] * pr[k] + pi[k] * pi[k]) * g;
    }
    float acc = acc2.x + acc2.y;

    #pragma unroll
    for (int off = 32; off > 0; off >>= 1) acc += __shfl_down(acc, off);
    if ((t & 63) == 0) partial[t >> 6] = acc;
    __syncthreads();
    if (t == 0) {
        float tot = 0.0f;
        #pragma unroll
        for (int k = 0; k < NT / 64; ++k) tot += partial[k];
        out[b] = tot + head_b[0];
    }
#undef GATEU
#undef GATEC
}

extern "C" void kernel_launch(void* const* d_in, const int* in_sizes, int n_in,
                              void* d_out, int out_size, void* d_ws, size_t ws_size,
                              hipStream_t stream) {
    const float* state  = (const float*)d_in[0];
    const float* params = (const float*)d_in[1];
    const float* head_w = (const float*)d_in[2];
    const float* head_b = (const float*)d_in[3];
    float* outp = (float*)d_out;
    qsim<<<BATCH, NT, 0, stream>>>(state, params, head_w, head_b, outp);
}